// Round 3
// baseline (688.274 us; speedup 1.0000x reference)
//
#include <hip/hip_runtime.h>
#include <hip/hip_bf16.h>

// Problem constants (from reference) — all float arrays are FP32.
#define NN     100000
#define EE     1600000
#define FE     32
#define FX     128
#define OX     128
#define OE     128
#define OUTC   (OX + OE)        // 256
#define NTILES (NN / 16)        // 6250, exact

// Partitioned aggregation geometry:
//   NPP     = 128 nodes per partition (row>>7)
//   NPART   = 782 partitions (max row 99999>>7 = 781)
//   PSTRIDE = 2816 edge slots per partition region (mean 2046, sd ~45: +17 sigma)
//   PCPAD   = 16 ints (64B) cursor padding to spread L2 slices
#define NPP     128
#define NPART   782
#define PSTRIDE 2816
#define PCPAD   16
#define ACCW    33              // LDS accumulator row stride (bank-conflict pad)

// d_ws layout:
//   agg   f32[NN*FE]           @ 0           (12,800,000 B)
//   flag  i32                  @ 12,800,000
//   pcur  i32[NPART*PCPAD]     @ 12,800,256  (50,048 B)
//   pbuf  i32[NPART*PSTRIDE]   @ 12,850,432  (8,808,448 B)
#define AGG_BYTES   12800000UL
#define FLAG_OFF    12800000UL
#define PCUR_OFF    12800256UL
#define PBUF_OFF    12850432UL
#define WS_NEED     (PBUF_OFF + (size_t)NPART * PSTRIDE * 4)

typedef unsigned short u16;
typedef short            shortx8  __attribute__((ext_vector_type(8)));
typedef float            floatx4  __attribute__((ext_vector_type(4)));
typedef int              intx4    __attribute__((ext_vector_type(4)));

__device__ __forceinline__ u16 f2b(float f) {
    union { float f; unsigned u; } v; v.f = f;
    unsigned u = v.u;
    return (u16)((u + 0x7FFFu + ((u >> 16) & 1u)) >> 16);   // RNE f32->bf16
}

// ---------------------------------------------------------------------------
// Kernel 0: zero pcur (12,512 ints); probe edge_index width (int32 vs int64)
// with the validated serial probe. flag=1 => int64 (odd words all zero).
// ---------------------------------------------------------------------------
__global__ __launch_bounds__(256) void init_kernel(
    int* __restrict__ pcur, int* __restrict__ flag, const int* __restrict__ ei) {
    int gid = blockIdx.x * 256 + threadIdx.x;
    if (gid * 4 < NPART * PCPAD) {            // 12512 % 4 == 0
        intx4 z = {0, 0, 0, 0};
        *(intx4*)(pcur + gid * 4) = z;
    }
    if (gid == 0) {
        int orv = 0;
        for (int j = 1; j < 256; j += 2) orv |= ei[j];
        *flag = (orv == 0) ? 1 : 0;
    }
}

// ---------------------------------------------------------------------------
// Kernel 1: partition-scatter. The atomic-rate fix: per block, ONE global
// atomic per touched partition (196 blocks x <=782 partitions ~= 153K global
// atomics, 10x fewer than the 1.6M per-edge atomics that cost ~115-145us in
// all three previous designs). Edge membership resolved with LDS atomics
// (block-local, cheap). Entries (localrow<<21 | e) land in dense fixed
// per-partition regions of pbuf (L2-absorbed writes).
// ---------------------------------------------------------------------------
__global__ __launch_bounds__(512) void part_kernel(
    const int* __restrict__ ei, const int* __restrict__ flag,
    int* __restrict__ pcur, int* __restrict__ pbuf) {
    __shared__ int h[NPART];
    __shared__ int gb[NPART];
    int tid = threadIdx.x;
    for (int i = tid; i < NPART; i += 512) h[i] = 0;
    __syncthreads();
    int is64 = *flag;
    int e0 = blockIdx.x * 8192;               // 196 blocks x 8192 >= EE
    int rows[16];
#pragma unroll
    for (int i = 0; i < 16; ++i) {
        int e = e0 + i * 512 + tid;
        int row = -1;
        if (e < EE) row = is64 ? ei[2 * (size_t)e] : ei[e];
        rows[i] = ((unsigned)row < (unsigned)NN) ? row : -1;
        if (rows[i] >= 0) atomicAdd(&h[rows[i] >> 7], 1);
    }
    __syncthreads();
    for (int b = tid; b < NPART; b += 512) {
        int c = h[b];
        gb[b] = c ? atomicAdd(pcur + b * PCPAD, c) : 0;
    }
    __syncthreads();
#pragma unroll
    for (int i = 0; i < 16; ++i) {
        int row = rows[i];
        if (row >= 0) {
            int e = e0 + i * 512 + tid;
            int p = row >> 7;
            int off = atomicAdd(&gb[p], 1);   // LDS cursor: base + local slot
            if (off < PSTRIDE)
                pbuf[(size_t)p * PSTRIDE + off] = ((row & 127) << 21) | e;
        }
    }
}

// ---------------------------------------------------------------------------
// Kernel 2: per-partition aggregate (replaces chase+gather). One block per
// partition: LDS accumulator f32[128][33] (pad 33: ds_add banks (lr+sub*4+c)
// %32, conflict-free across edge slots). Edge list read COALESCED from the
// compact region; each ea row read once as 8 lanes x 16B = 128B; 8 rounds of
// independent loads per wave hide latency. agg written coalesced.
// ---------------------------------------------------------------------------
__global__ __launch_bounds__(256) void agg_kernel(
    const int* __restrict__ pcur, const int* __restrict__ pbuf,
    const float* __restrict__ ea, float* __restrict__ agg) {
    __shared__ float acc[NPP * ACCW];         // 16,896 B
    __shared__ int sent[256];
    int tid = threadIdx.x;
    int p = blockIdx.x;
    for (int i = tid; i < NPP * ACCW; i += 256) acc[i] = 0.f;
    int cnt = pcur[p * PCPAD];
    if (cnt > PSTRIDE) cnt = PSTRIDE;         // defensive (statistically never)
    const int* seg = pbuf + (size_t)p * PSTRIDE;
    int es = tid >> 3, sub = tid & 7;
    for (int base = 0; base < cnt; base += 256) {
        int nb = cnt - base; if (nb > 256) nb = 256;
        __syncthreads();                       // protects sent reuse + acc init
        if (tid < nb) sent[tid] = seg[base + tid];
        __syncthreads();
#pragma unroll
        for (int r = 0; r < 8; ++r) {
            int idx = r * 32 + es;
            if (idx < nb) {
                int entry = sent[idx];        // positive: 28 bits used
                int lr = entry >> 21;         // 0..127
                int e  = entry & 0x1FFFFF;    // EE < 2^21
                floatx4 v = *(const floatx4*)(ea + (size_t)e * FE + sub * 4);
                int b = lr * ACCW + sub * 4;
                atomicAdd(&acc[b + 0], v[0]); // native ds f32 add
                atomicAdd(&acc[b + 1], v[1]);
                atomicAdd(&acc[b + 2], v[2]);
                atomicAdd(&acc[b + 3], v[3]);
            }
        }
    }
    __syncthreads();
#pragma unroll
    for (int pass = 0; pass < 4; ++pass) {
        int nl = pass * 32 + es;
        int node = p * NPP + nl;
        if (node < NN) {
            int b = nl * ACCW + sub * 4;      // scalar LDS reads: b*4 not 16B-aligned
            floatx4 o = {acc[b + 0], acc[b + 1], acc[b + 2], acc[b + 3]};
            *(floatx4*)(agg + (size_t)node * FE + sub * 4) = o;
        }
    }
}

// ---------------------------------------------------------------------------
// Fallback kernels (atomic path) if ws_size < WS_NEED.
// ---------------------------------------------------------------------------
__global__ __launch_bounds__(256) void zero_probe_kernel(
    float* __restrict__ agg, int* __restrict__ flag, const int* __restrict__ ei) {
    int gid = blockIdx.x * 256 + threadIdx.x;
    floatx4 z = {0.f, 0.f, 0.f, 0.f};
    *(floatx4*)(agg + (size_t)gid * 4) = z;
    if (gid == 0) {
        int orv = 0;
        for (int j = 1; j < 256; j += 2) orv |= ei[j];
        *flag = (orv == 0) ? 1 : 0;
    }
}

__global__ __launch_bounds__(256) void scatter_kernel(
    const int* __restrict__ rows, const float* __restrict__ ea,
    float* __restrict__ agg, const int* __restrict__ flag) {
    int gid = blockIdx.x * 256 + threadIdx.x;
    int e  = gid >> 3;
    int fg = (gid & 7) << 2;
    int is64 = *flag;
    int row = is64 ? rows[2 * (size_t)e] : rows[e];
    floatx4 v = *(const floatx4*)(ea + (size_t)e * FE + fg);
    float* dst = agg + (size_t)row * FE + fg;
#pragma unroll
    for (int j = 0; j < 4; ++j) unsafeAtomicAdd(dst + j, v[j]);
}

// ---------------------------------------------------------------------------
// Kernel 3: fused  out[n] = relu([x@Wx+bx , agg@We+be])   (f32 in, f32 out)
// One wave per 16-row M-tile; f32->bf16 on the fly; MFMA 16x16x32 bf16.
// Frag layouts (m89/m91/m120-verified):
//   A: lane l holds A[m=l&15][k=(l>>4)*8+j], j=0..7
//   B: lane l holds B[k=(l>>4)*8+j][n=l&15]
//   D: lane l reg r holds D[(l>>4)*4+r][l&15]
// ---------------------------------------------------------------------------
__global__ __launch_bounds__(256) void fused_gemm_kernel(
    const float* __restrict__ x, const float* __restrict__ agg,
    const float* __restrict__ Wx, const float* __restrict__ bx,
    const float* __restrict__ We, const float* __restrict__ be,
    float* __restrict__ out, int nwaves) {
    // fragment-order LDS (bf16): frag f, lane, 8 contiguous shorts (16B/lane)
    __shared__ short fragWx[32][64][8];   // f = kt*8+nt   32KB
    __shared__ short fragWe[8][64][8];    // f = nt         8KB

    int tid = threadIdx.x;

    for (int c = tid; c < (FX * OX) / 4; c += 256) {
        int base = c * 4;
        int k = base >> 7;
        int n = base & 127;
        floatx4 v = *(const floatx4*)(Wx + base);
        int kt = k >> 5, jj = k & 7, halfk = (k >> 3) & 3;
#pragma unroll
        for (int u = 0; u < 4; ++u) {
            int nn = n + u;
            fragWx[kt * 8 + (nn >> 4)][halfk * 16 + (nn & 15)][jj] = (short)f2b(v[u]);
        }
    }
    for (int c = tid; c < (FE * OE) / 4; c += 256) {
        int base = c * 4;
        int k = base >> 7;
        int n = base & 127;
        floatx4 v = *(const floatx4*)(We + base);
        int jj = k & 7, halfk = (k >> 3) & 3;
#pragma unroll
        for (int u = 0; u < 4; ++u) {
            int nn = n + u;
            fragWe[nn >> 4][halfk * 16 + (nn & 15)][jj] = (short)f2b(v[u]);
        }
    }
    __syncthreads();

    int wave = tid >> 6, lane = tid & 63;
    int q = lane >> 4, i = lane & 15;

    shortx8 bwe[8];
    float bxv[8], bev[8];
#pragma unroll
    for (int nt = 0; nt < 8; ++nt) {
        bwe[nt] = *(const shortx8*)&fragWe[nt][lane][0];
        bxv[nt] = bx[nt * 16 + i];
        bev[nt] = be[nt * 16 + i];
    }

    int gwave = blockIdx.x * 4 + wave;
    for (int mt = gwave; mt < NTILES; mt += nwaves) {
        int m0 = mt << 4;
        int arow = m0 + i;

        const float* xp = x + (size_t)arow * FX + q * 8;
        shortx8 ax[4];
#pragma unroll
        for (int kt = 0; kt < 4; ++kt) {
            floatx4 a0 = *(const floatx4*)(xp + kt * 32);
            floatx4 a1 = *(const floatx4*)(xp + kt * 32 + 4);
#pragma unroll
            for (int j = 0; j < 4; ++j) {
                ax[kt][j]     = (short)f2b(a0[j]);
                ax[kt][4 + j] = (short)f2b(a1[j]);
            }
        }

        const float* ap = agg + (size_t)arow * FE + q * 8;
        floatx4 g0 = *(const floatx4*)ap;
        floatx4 g1 = *(const floatx4*)(ap + 4);
        shortx8 aagg;
#pragma unroll
        for (int j = 0; j < 4; ++j) {
            aagg[j]     = (short)f2b(g0[j]);
            aagg[4 + j] = (short)f2b(g1[j]);
        }

#pragma unroll
        for (int nt = 0; nt < 8; ++nt) {
            floatx4 acc = {0.f, 0.f, 0.f, 0.f};
#pragma unroll
            for (int kt = 0; kt < 4; ++kt) {
                shortx8 b = *(const shortx8*)&fragWx[kt * 8 + nt][lane][0];
                acc = __builtin_amdgcn_mfma_f32_16x16x32_bf16(ax[kt], b, acc, 0, 0, 0);
            }
            floatx4 acche = {0.f, 0.f, 0.f, 0.f};
            acche = __builtin_amdgcn_mfma_f32_16x16x32_bf16(aagg, bwe[nt], acche, 0, 0, 0);
#pragma unroll
            for (int r = 0; r < 4; ++r) {
                int orow = m0 + q * 4 + r;
                float* op = out + (size_t)orow * OUTC + nt * 16 + i;
                float h = acc[r] + bxv[nt];
                op[0]  = h > 0.f ? h : 0.f;
                float g = acche[r] + bev[nt];
                op[OX] = g > 0.f ? g : 0.f;
            }
        }
    }
}

extern "C" void kernel_launch(void* const* d_in, const int* in_sizes, int n_in,
                              void* d_out, int out_size, void* d_ws, size_t ws_size,
                              hipStream_t stream) {
    const float* x  = (const float*)d_in[0];   // [N, FX] f32
    const int*   ei = (const int*)d_in[1];     // [2, E] int (width probed)
    const float* ea = (const float*)d_in[2];   // [E, FE] f32
    const float* Wx = (const float*)d_in[3];   // [FX, OX] f32
    const float* bx = (const float*)d_in[4];   // [OX] f32
    const float* We = (const float*)d_in[5];   // [FE, OE] f32
    const float* be = (const float*)d_in[6];   // [OE] f32
    float* out = (float*)d_out;                // [N, 256] f32

    float* agg  = (float*)d_ws;
    int*   flagC= (int*)((char*)d_ws + FLAG_OFF);
    int*   pcur = (int*)((char*)d_ws + PCUR_OFF);
    int*   pbuf = (int*)((char*)d_ws + PBUF_OFF);

    if (ws_size >= WS_NEED) {
        // ---- partitioned-aggregation path ----
        init_kernel<<<(NPART * PCPAD / 4 + 255) / 256, 256, 0, stream>>>(pcur, flagC, ei);
        part_kernel<<<(EE + 8191) / 8192, 512, 0, stream>>>(ei, flagC, pcur, pbuf);
        agg_kernel<<<NPART, 256, 0, stream>>>(pcur, pbuf, ea, agg);
    } else {
        // ---- fallback: atomic scatter ----
        int* flagA = (int*)((char*)d_ws + AGG_BYTES);
        zero_probe_kernel<<<(NN * FE) / 4 / 256, 256, 0, stream>>>(agg, flagA, ei);
        scatter_kernel<<<(EE * 8) / 256, 256, 0, stream>>>(ei, ea, agg, flagA);
    }

    // gemm: 1563 blocks x 4 waves = 6252 waves >= 6250 tiles (1 tile/wave)
    const int blocks = 1563;
    fused_gemm_kernel<<<blocks, 256, 0, stream>>>(x, agg, Wx, bx, We, be, out,
                                                  blocks * 4);
}

// Round 4
// 449.268 us; speedup vs baseline: 1.5320x; 1.5320x over previous
//
#include <hip/hip_runtime.h>
#include <hip/hip_bf16.h>

// Problem constants (from reference) — all float arrays are FP32.
#define NN     100000
#define EE     1600000
#define FE     32
#define FX     128
#define OX     128
#define OE     128
#define OUTC   (OX + OE)        // 256
#define NTILES (NN / 16)        // 6250, exact

// Partitioned aggregation geometry:
//   NPP     = 128 nodes per partition (row>>7)
//   NPART   = 782 partitions (max row 99999>>7 = 781)
//   PSTRIDE = 2816 edge slots per partition region (mean 2046, sd ~45)
//   PCPAD   = 16 ints (64B) cursor padding to spread L2 slices
#define NPP     128
#define NPART   782
#define PSTRIDE 2816
#define PCPAD   16

// d_ws layout:
//   agg   f32[NN*FE]           @ 0           (12,800,000 B)
//   flag  i32                  @ 12,800,000
//   pcur  i32[NPART*PCPAD]     @ 12,800,256  (50,048 B)
//   pbuf  i32[NPART*PSTRIDE]   @ 12,850,432  (8,808,448 B)  block-order entries
//   sbuf  i32[NPART*PSTRIDE]   @ 21,658,880  (8,808,448 B)  node-sorted entries
//   pack  i32[NN]              @ 30,467,328  (400,000 B)    (off<<7)|deg
#define AGG_BYTES   12800000UL
#define FLAG_OFF    12800000UL
#define PCUR_OFF    12800256UL
#define PBUF_OFF    12850432UL
#define SBUF_OFF    21658880UL
#define PACK_OFF    30467328UL
#define WS_NEED     (PACK_OFF + (size_t)NN * 4)

typedef unsigned short u16;
typedef short            shortx8  __attribute__((ext_vector_type(8)));
typedef float            floatx4  __attribute__((ext_vector_type(4)));
typedef int              intx4    __attribute__((ext_vector_type(4)));

__device__ __forceinline__ u16 f2b(float f) {
    union { float f; unsigned u; } v; v.f = f;
    unsigned u = v.u;
    return (u16)((u + 0x7FFFu + ((u >> 16) & 1u)) >> 16);   // RNE f32->bf16
}

// ---------------------------------------------------------------------------
// Kernel 0: zero pcur (12,512 ints); probe edge_index width (int32 vs int64)
// with the validated serial probe. flag=1 => int64 (odd words all zero).
// ---------------------------------------------------------------------------
__global__ __launch_bounds__(256) void init_kernel(
    int* __restrict__ pcur, int* __restrict__ flag, const int* __restrict__ ei) {
    int gid = blockIdx.x * 256 + threadIdx.x;
    if (gid * 4 < NPART * PCPAD) {            // 12512 % 4 == 0
        intx4 z = {0, 0, 0, 0};
        *(intx4*)(pcur + gid * 4) = z;
    }
    if (gid == 0) {
        int orv = 0;
        for (int j = 1; j < 256; j += 2) orv |= ei[j];
        *flag = (orv == 0) ? 1 : 0;
    }
}

// ---------------------------------------------------------------------------
// Kernel 1: partition-scatter (R3-proven). Per block ONE global atomic per
// touched partition (~153K total vs 1.6M per-edge: the 10x atomic-rate cut).
// Edge membership resolved with LDS atomics. Entries (localrow<<21 | e) land
// in dense per-partition regions of pbuf (runs of ~10 entries per
// block-partition: near-full line coverage, L2-absorbed).
// ---------------------------------------------------------------------------
__global__ __launch_bounds__(512) void part_kernel(
    const int* __restrict__ ei, const int* __restrict__ flag,
    int* __restrict__ pcur, int* __restrict__ pbuf) {
    __shared__ int h[NPART];
    __shared__ int gb[NPART];
    int tid = threadIdx.x;
    for (int i = tid; i < NPART; i += 512) h[i] = 0;
    __syncthreads();
    int is64 = *flag;
    int e0 = blockIdx.x * 8192;               // 196 blocks x 8192 >= EE
    int rows[16];
#pragma unroll
    for (int i = 0; i < 16; ++i) {
        int e = e0 + i * 512 + tid;
        int row = -1;
        if (e < EE) row = is64 ? ei[2 * (size_t)e] : ei[e];
        rows[i] = ((unsigned)row < (unsigned)NN) ? row : -1;
        if (rows[i] >= 0) atomicAdd(&h[rows[i] >> 7], 1);
    }
    __syncthreads();
    for (int b = tid; b < NPART; b += 512) {
        int c = h[b];
        gb[b] = c ? atomicAdd(pcur + b * PCPAD, c) : 0;
    }
    __syncthreads();
#pragma unroll
    for (int i = 0; i < 16; ++i) {
        int row = rows[i];
        if (row >= 0) {
            int e = e0 + i * 512 + tid;
            int p = row >> 7;
            int off = atomicAdd(&gb[p], 1);   // LDS cursor: base + local slot
            if (off < PSTRIDE)
                pbuf[(size_t)p * PSTRIDE + off] = ((row & 127) << 21) | e;
        }
    }
}

// ---------------------------------------------------------------------------
// Kernel 2: per-partition LDS counting sort (replaces LL chase; no global
// atomics). One block per partition, 1.5KB LDS: histogram over 128 local
// rows -> 64-lane shfl scan -> scatter into node-contiguous sbuf. All
// conflict resolution is LDS atomics; global reads/writes coalesced.
// pack[node] = (sbuf_offset<<7)|deg  (off < 2^22, deg <= 127).
// ---------------------------------------------------------------------------
__global__ __launch_bounds__(256) void sort_kernel(
    const int* __restrict__ pcur, const int* __restrict__ pbuf,
    int* __restrict__ sbuf, int* __restrict__ pack) {
    __shared__ int hist[NPP];
    __shared__ int boff[NPP];
    __shared__ int cur[NPP];
    int tid = threadIdx.x;
    int p = blockIdx.x;
    if (tid < NPP) hist[tid] = 0;
    int cnt = pcur[p * PCPAD];
    if (cnt > PSTRIDE) cnt = PSTRIDE;         // defensive (statistically never)
    const int* seg = pbuf + (size_t)p * PSTRIDE;
    __syncthreads();
#pragma unroll 4
    for (int i = tid; i < cnt; i += 256)      // coalesced
        atomicAdd(&hist[((unsigned)seg[i]) >> 21], 1);
    __syncthreads();
    if (tid < 64) {                           // exclusive scan of 128 bins
        int a = hist[2 * tid], b = hist[2 * tid + 1];
        int s = a + b;
        int pre = s;
#pragma unroll
        for (int off = 1; off < 64; off <<= 1) {
            int t = __shfl_up(pre, off, 64);
            if (tid >= off) pre += t;
        }
        boff[2 * tid]     = pre - s;
        boff[2 * tid + 1] = pre - b;
        cur[2 * tid]      = pre - s;
        cur[2 * tid + 1]  = pre - b;
    }
    __syncthreads();
    int* dst = sbuf + (size_t)p * PSTRIDE;
#pragma unroll 4
    for (int i = tid; i < cnt; i += 256) {
        int en = seg[i];
        int o = atomicAdd(&cur[((unsigned)en) >> 21], 1);
        dst[o] = en;
    }
    if (tid < NPP) {
        int node = p * NPP + tid;
        if (node < NN) {
            int d = hist[tid];
            if (d > 127) d = 127;             // defensive: keep pack well-formed
            unsigned off = (unsigned)(p * PSTRIDE + boff[tid]);
            pack[node] = (int)((off << 7) | (unsigned)d);
        }
    }
}

// ---------------------------------------------------------------------------
// Kernel 3: gather-sum (R1/R2-proven wave-per-node MLP structure):
//   g   = lane>>3 : edge group (8-16 edges concurrently in flight per wave)
//   sub = lane&7  : feature quad (floatx4; 8 lanes x 16B = one 128B edge row)
// ids staged from node-contiguous sbuf (mask off localrow bits).
// Cross-group reduce: 3 rounds of __shfl_xor. Lanes g==0 store 128B row.
// ---------------------------------------------------------------------------
__global__ __launch_bounds__(256) void gather_kernel(
    const int* __restrict__ pack, const int* __restrict__ sbuf,
    const float* __restrict__ ea, float* __restrict__ agg) {
    __shared__ int ids[4][128];
    int wave = threadIdx.x >> 6, lane = threadIdx.x & 63;
    int node = blockIdx.x * 4 + wave;         // grid exact N/4 blocks
    int pk = pack[node];
    int off = (int)(((unsigned)pk) >> 7);
    int deg = pk & 127;
    for (int j = lane; j < deg; j += 64)
        ids[wave][j] = sbuf[off + j] & 0x1FFFFF;
    __syncthreads();

    int g = lane >> 3, sub = lane & 7;
    floatx4 acc0 = {0.f, 0.f, 0.f, 0.f};
    floatx4 acc1 = {0.f, 0.f, 0.f, 0.f};
    int j = g;
    for (; j + 8 < deg; j += 16) {            // 16 independent loads in flight
        acc0 += *(const floatx4*)(ea + (size_t)ids[wave][j] * FE + sub * 4);
        acc1 += *(const floatx4*)(ea + (size_t)ids[wave][j + 8] * FE + sub * 4);
    }
    if (j < deg)
        acc0 += *(const floatx4*)(ea + (size_t)ids[wave][j] * FE + sub * 4);
    acc0 += acc1;

#pragma unroll
    for (int m = 8; m <= 32; m <<= 1) {
#pragma unroll
        for (int c = 0; c < 4; ++c)
            acc0[c] += __shfl_xor(acc0[c], m, 64);
    }
    if (g == 0)
        *(floatx4*)(agg + (size_t)node * FE + sub * 4) = acc0;
}

// ---------------------------------------------------------------------------
// Fallback kernels (atomic path) if ws_size < WS_NEED.
// ---------------------------------------------------------------------------
__global__ __launch_bounds__(256) void zero_probe_kernel(
    float* __restrict__ agg, int* __restrict__ flag, const int* __restrict__ ei) {
    int gid = blockIdx.x * 256 + threadIdx.x;
    floatx4 z = {0.f, 0.f, 0.f, 0.f};
    *(floatx4*)(agg + (size_t)gid * 4) = z;
    if (gid == 0) {
        int orv = 0;
        for (int j = 1; j < 256; j += 2) orv |= ei[j];
        *flag = (orv == 0) ? 1 : 0;
    }
}

__global__ __launch_bounds__(256) void scatter_kernel(
    const int* __restrict__ rows, const float* __restrict__ ea,
    float* __restrict__ agg, const int* __restrict__ flag) {
    int gid = blockIdx.x * 256 + threadIdx.x;
    int e  = gid >> 3;
    int fg = (gid & 7) << 2;
    int is64 = *flag;
    int row = is64 ? rows[2 * (size_t)e] : rows[e];
    floatx4 v = *(const floatx4*)(ea + (size_t)e * FE + fg);
    float* dst = agg + (size_t)row * FE + fg;
#pragma unroll
    for (int j = 0; j < 4; ++j) unsafeAtomicAdd(dst + j, v[j]);
}

// ---------------------------------------------------------------------------
// Kernel 4: fused  out[n] = relu([x@Wx+bx , agg@We+be])   (f32 in, f32 out)
// One wave per 16-row M-tile; f32->bf16 on the fly; MFMA 16x16x32 bf16.
// Frag layouts (m89/m91/m120-verified):
//   A: lane l holds A[m=l&15][k=(l>>4)*8+j], j=0..7
//   B: lane l holds B[k=(l>>4)*8+j][n=l&15]
//   D: lane l reg r holds D[(l>>4)*4+r][l&15]
// ---------------------------------------------------------------------------
__global__ __launch_bounds__(256) void fused_gemm_kernel(
    const float* __restrict__ x, const float* __restrict__ agg,
    const float* __restrict__ Wx, const float* __restrict__ bx,
    const float* __restrict__ We, const float* __restrict__ be,
    float* __restrict__ out, int nwaves) {
    // fragment-order LDS (bf16): frag f, lane, 8 contiguous shorts (16B/lane)
    __shared__ short fragWx[32][64][8];   // f = kt*8+nt   32KB
    __shared__ short fragWe[8][64][8];    // f = nt         8KB

    int tid = threadIdx.x;

    for (int c = tid; c < (FX * OX) / 4; c += 256) {
        int base = c * 4;
        int k = base >> 7;
        int n = base & 127;
        floatx4 v = *(const floatx4*)(Wx + base);
        int kt = k >> 5, jj = k & 7, halfk = (k >> 3) & 3;
#pragma unroll
        for (int u = 0; u < 4; ++u) {
            int nn = n + u;
            fragWx[kt * 8 + (nn >> 4)][halfk * 16 + (nn & 15)][jj] = (short)f2b(v[u]);
        }
    }
    for (int c = tid; c < (FE * OE) / 4; c += 256) {
        int base = c * 4;
        int k = base >> 7;
        int n = base & 127;
        floatx4 v = *(const floatx4*)(We + base);
        int jj = k & 7, halfk = (k >> 3) & 3;
#pragma unroll
        for (int u = 0; u < 4; ++u) {
            int nn = n + u;
            fragWe[nn >> 4][halfk * 16 + (nn & 15)][jj] = (short)f2b(v[u]);
        }
    }
    __syncthreads();

    int wave = tid >> 6, lane = tid & 63;
    int q = lane >> 4, i = lane & 15;

    shortx8 bwe[8];
    float bxv[8], bev[8];
#pragma unroll
    for (int nt = 0; nt < 8; ++nt) {
        bwe[nt] = *(const shortx8*)&fragWe[nt][lane][0];
        bxv[nt] = bx[nt * 16 + i];
        bev[nt] = be[nt * 16 + i];
    }

    int gwave = blockIdx.x * 4 + wave;
    for (int mt = gwave; mt < NTILES; mt += nwaves) {
        int m0 = mt << 4;
        int arow = m0 + i;

        const float* xp = x + (size_t)arow * FX + q * 8;
        shortx8 ax[4];
#pragma unroll
        for (int kt = 0; kt < 4; ++kt) {
            floatx4 a0 = *(const floatx4*)(xp + kt * 32);
            floatx4 a1 = *(const floatx4*)(xp + kt * 32 + 4);
#pragma unroll
            for (int j = 0; j < 4; ++j) {
                ax[kt][j]     = (short)f2b(a0[j]);
                ax[kt][4 + j] = (short)f2b(a1[j]);
            }
        }

        const float* ap = agg + (size_t)arow * FE + q * 8;
        floatx4 g0 = *(const floatx4*)ap;
        floatx4 g1 = *(const floatx4*)(ap + 4);
        shortx8 aagg;
#pragma unroll
        for (int j = 0; j < 4; ++j) {
            aagg[j]     = (short)f2b(g0[j]);
            aagg[4 + j] = (short)f2b(g1[j]);
        }

#pragma unroll
        for (int nt = 0; nt < 8; ++nt) {
            floatx4 acc = {0.f, 0.f, 0.f, 0.f};
#pragma unroll
            for (int kt = 0; kt < 4; ++kt) {
                shortx8 b = *(const shortx8*)&fragWx[kt * 8 + nt][lane][0];
                acc = __builtin_amdgcn_mfma_f32_16x16x32_bf16(ax[kt], b, acc, 0, 0, 0);
            }
            floatx4 acche = {0.f, 0.f, 0.f, 0.f};
            acche = __builtin_amdgcn_mfma_f32_16x16x32_bf16(aagg, bwe[nt], acche, 0, 0, 0);
#pragma unroll
            for (int r = 0; r < 4; ++r) {
                int orow = m0 + q * 4 + r;
                float* op = out + (size_t)orow * OUTC + nt * 16 + i;
                float h = acc[r] + bxv[nt];
                op[0]  = h > 0.f ? h : 0.f;
                float g = acche[r] + bev[nt];
                op[OX] = g > 0.f ? g : 0.f;
            }
        }
    }
}

extern "C" void kernel_launch(void* const* d_in, const int* in_sizes, int n_in,
                              void* d_out, int out_size, void* d_ws, size_t ws_size,
                              hipStream_t stream) {
    const float* x  = (const float*)d_in[0];   // [N, FX] f32
    const int*   ei = (const int*)d_in[1];     // [2, E] int (width probed)
    const float* ea = (const float*)d_in[2];   // [E, FE] f32
    const float* Wx = (const float*)d_in[3];   // [FX, OX] f32
    const float* bx = (const float*)d_in[4];   // [OX] f32
    const float* We = (const float*)d_in[5];   // [FE, OE] f32
    const float* be = (const float*)d_in[6];   // [OE] f32
    float* out = (float*)d_out;                // [N, 256] f32

    float* agg  = (float*)d_ws;
    int*   flagC= (int*)((char*)d_ws + FLAG_OFF);
    int*   pcur = (int*)((char*)d_ws + PCUR_OFF);
    int*   pbuf = (int*)((char*)d_ws + PBUF_OFF);
    int*   sbuf = (int*)((char*)d_ws + SBUF_OFF);
    int*   pack = (int*)((char*)d_ws + PACK_OFF);

    if (ws_size >= WS_NEED) {
        // ---- partition + counting-sort CSR path ----
        init_kernel<<<(NPART * PCPAD / 4 + 255) / 256, 256, 0, stream>>>(pcur, flagC, ei);
        part_kernel<<<(EE + 8191) / 8192, 512, 0, stream>>>(ei, flagC, pcur, pbuf);
        sort_kernel<<<NPART, 256, 0, stream>>>(pcur, pbuf, sbuf, pack);
        gather_kernel<<<NN / 4, 256, 0, stream>>>(pack, sbuf, ea, agg);
    } else {
        // ---- fallback: atomic scatter ----
        int* flagA = (int*)((char*)d_ws + AGG_BYTES);
        zero_probe_kernel<<<(NN * FE) / 4 / 256, 256, 0, stream>>>(agg, flagA, ei);
        scatter_kernel<<<(EE * 8) / 256, 256, 0, stream>>>(ei, ea, agg, flagA);
    }

    // gemm: 1563 blocks x 4 waves = 6252 waves >= 6250 tiles (1 tile/wave)
    const int blocks = 1563;
    fused_gemm_kernel<<<blocks, 256, 0, stream>>>(x, agg, Wx, bx, We, be, out,
                                                  blocks * 4);
}

// Round 5
// 425.801 us; speedup vs baseline: 1.6164x; 1.0551x over previous
//
#include <hip/hip_runtime.h>
#include <hip/hip_bf16.h>

// Problem constants (from reference) — all float arrays are FP32.
#define NN     100000
#define EE     1600000
#define FE     32
#define FX     128
#define OX     128
#define OE     128
#define OUTC   (OX + OE)        // 256
#define NTILES (NN / 16)        // 6250, exact

// Partitioned aggregation geometry:
//   NPP     = 128 nodes per partition (row>>7)
//   NPART   = 782 partitions (max row 99999>>7 = 781)
//   PSTRIDE = 2816 edge slots per partition region (mean 2046, sd ~45)
//   PCPAD   = 16 ints (64B) cursor padding to spread L2 slices
#define NPP     128
#define NPART   782
#define PSTRIDE 2816
#define PCPAD   16

// d_ws layout:
//   agg   f32[NN*FE]           @ 0           (12,800,000 B)
//   flag  i32                  @ 12,800,000
//   pcur  i32[NPART*PCPAD]     @ 12,800,256  (50,048 B)
//   pbuf  i32[NPART*PSTRIDE]   @ 12,850,432  (8,808,448 B)  block-order entries
//   sbuf  i32[NPART*PSTRIDE]   @ 21,658,880  (8,808,448 B)  node-sorted entries
//   pack  i32[NN]              @ 30,467,328  (400,000 B)    (off<<7)|deg
//   wbuf  bf16 frags           @ 30,867,328  (73,728 B)     wfx[32][64][8], wfe[8][64][8]
#define AGG_BYTES   12800000UL
#define FLAG_OFF    12800000UL
#define PCUR_OFF    12800256UL
#define PBUF_OFF    12850432UL
#define SBUF_OFF    21658880UL
#define PACK_OFF    30467328UL
#define WBUF_OFF    30867328UL
#define WFE_ELEMS   (32 * 64 * 8)             // wfx shorts; wfe follows
#define WS_NEED     (WBUF_OFF + 73728UL)

typedef unsigned short u16;
typedef short            shortx8  __attribute__((ext_vector_type(8)));
typedef float            floatx4  __attribute__((ext_vector_type(4)));
typedef int              intx4    __attribute__((ext_vector_type(4)));

__device__ __forceinline__ u16 f2b(float f) {
    union { float f; unsigned u; } v; v.f = f;
    unsigned u = v.u;
    return (u16)((u + 0x7FFFu + ((u >> 16) & 1u)) >> 16);   // RNE f32->bf16
}

// ---------------------------------------------------------------------------
// Kernel 0: zero pcur (12,512 ints); probe edge_index width (int32 vs int64)
// with the validated serial probe. flag=1 => int64 (odd words all zero).
// ---------------------------------------------------------------------------
__global__ __launch_bounds__(256) void init_kernel(
    int* __restrict__ pcur, int* __restrict__ flag, const int* __restrict__ ei) {
    int gid = blockIdx.x * 256 + threadIdx.x;
    if (gid * 4 < NPART * PCPAD) {            // 12512 % 4 == 0
        intx4 z = {0, 0, 0, 0};
        *(intx4*)(pcur + gid * 4) = z;
    }
    if (gid == 0) {
        int orv = 0;
        for (int j = 1; j < 256; j += 2) orv |= ei[j];
        *flag = (orv == 0) ? 1 : 0;
    }
}

// ---------------------------------------------------------------------------
// Kernel 1: weight prep (one-shot, ~5120 threads). Writes bf16 fragment-
// layout weights to global wbuf ONCE, so the GEMM needs no per-block LDS
// staging (was: 1563 blocks x 80KB redundant reads + 20K f2b + barrier each).
// Layout identical to the previous LDS staging (m89/m91-verified B-frag):
//   wfx[(kt*8 + (n>>4))*64 + halfk*16 + (n&15)][jj],  kt=k>>5, halfk=(k>>3)&3, jj=k&7
// ---------------------------------------------------------------------------
__global__ __launch_bounds__(256) void prep_kernel(
    const float* __restrict__ Wx, const float* __restrict__ We,
    short* __restrict__ wbuf) {
    int c = blockIdx.x * 256 + threadIdx.x;   // 20 blocks x 256 = 5120 exact
    short* wfx = wbuf;
    short* wfe = wbuf + WFE_ELEMS;
    if (c < (FX * OX) / 4) {
        int base = c * 4;
        int k = base >> 7;
        int n = base & 127;
        floatx4 v = *(const floatx4*)(Wx + base);
        int kt = k >> 5, jj = k & 7, halfk = (k >> 3) & 3;
#pragma unroll
        for (int u = 0; u < 4; ++u) {
            int nn = n + u;
            wfx[((kt * 8 + (nn >> 4)) * 64 + halfk * 16 + (nn & 15)) * 8 + jj] =
                (short)f2b(v[u]);
        }
    } else if (c < (FX * OX) / 4 + (FE * OE) / 4) {
        int base = (c - (FX * OX) / 4) * 4;
        int k = base >> 7;
        int n = base & 127;
        floatx4 v = *(const floatx4*)(We + base);
        int jj = k & 7, halfk = (k >> 3) & 3;
#pragma unroll
        for (int u = 0; u < 4; ++u) {
            int nn = n + u;
            wfe[((nn >> 4) * 64 + halfk * 16 + (nn & 15)) * 8 + jj] =
                (short)f2b(v[u]);
        }
    }
}

// ---------------------------------------------------------------------------
// Kernel 2: partition-scatter (R3/R4-proven; now 1024-thread blocks: 8 load
// rounds instead of 16, 2x waves/block for latency hiding; global atomic
// count unchanged at ~153K = one per touched (block, partition)).
// Entries (localrow<<21 | e) land in dense per-partition regions of pbuf.
// ---------------------------------------------------------------------------
__global__ __launch_bounds__(1024) void part_kernel(
    const int* __restrict__ ei, const int* __restrict__ flag,
    int* __restrict__ pcur, int* __restrict__ pbuf) {
    __shared__ int h[NPART];
    __shared__ int gb[NPART];
    int tid = threadIdx.x;
    if (tid < NPART) h[tid] = 0;
    __syncthreads();
    int is64 = *flag;
    int e0 = blockIdx.x * 8192;               // 196 blocks x 8192 >= EE
    int rows[8];
#pragma unroll
    for (int i = 0; i < 8; ++i) {
        int e = e0 + i * 1024 + tid;
        int row = -1;
        if (e < EE) row = is64 ? ei[2 * (size_t)e] : ei[e];
        rows[i] = ((unsigned)row < (unsigned)NN) ? row : -1;
        if (rows[i] >= 0) atomicAdd(&h[rows[i] >> 7], 1);
    }
    __syncthreads();
    if (tid < NPART) {
        int c = h[tid];
        gb[tid] = c ? atomicAdd(pcur + tid * PCPAD, c) : 0;
    }
    __syncthreads();
#pragma unroll
    for (int i = 0; i < 8; ++i) {
        int row = rows[i];
        if (row >= 0) {
            int e = e0 + i * 1024 + tid;
            int p = row >> 7;
            int off = atomicAdd(&gb[p], 1);   // LDS cursor: base + local slot
            if (off < PSTRIDE)
                pbuf[(size_t)p * PSTRIDE + off] = ((row & 127) << 21) | e;
        }
    }
}

// ---------------------------------------------------------------------------
// Kernel 3: per-partition LDS counting sort (R4-proven, unchanged). One block
// per partition: histogram over 128 local rows -> 64-lane shfl scan ->
// scatter into node-contiguous sbuf. pack[node] = (sbuf_offset<<7)|deg.
// ---------------------------------------------------------------------------
__global__ __launch_bounds__(256) void sort_kernel(
    const int* __restrict__ pcur, const int* __restrict__ pbuf,
    int* __restrict__ sbuf, int* __restrict__ pack) {
    __shared__ int hist[NPP];
    __shared__ int boff[NPP];
    __shared__ int cur[NPP];
    int tid = threadIdx.x;
    int p = blockIdx.x;
    if (tid < NPP) hist[tid] = 0;
    int cnt = pcur[p * PCPAD];
    if (cnt > PSTRIDE) cnt = PSTRIDE;         // defensive (statistically never)
    const int* seg = pbuf + (size_t)p * PSTRIDE;
    __syncthreads();
#pragma unroll 4
    for (int i = tid; i < cnt; i += 256)      // coalesced
        atomicAdd(&hist[((unsigned)seg[i]) >> 21], 1);
    __syncthreads();
    if (tid < 64) {                           // exclusive scan of 128 bins
        int a = hist[2 * tid], b = hist[2 * tid + 1];
        int s = a + b;
        int pre = s;
#pragma unroll
        for (int off = 1; off < 64; off <<= 1) {
            int t = __shfl_up(pre, off, 64);
            if (tid >= off) pre += t;
        }
        boff[2 * tid]     = pre - s;
        boff[2 * tid + 1] = pre - b;
        cur[2 * tid]      = pre - s;
        cur[2 * tid + 1]  = pre - b;
    }
    __syncthreads();
    int* dst = sbuf + (size_t)p * PSTRIDE;
#pragma unroll 4
    for (int i = tid; i < cnt; i += 256) {
        int en = seg[i];
        int o = atomicAdd(&cur[((unsigned)en) >> 21], 1);
        dst[o] = en;
    }
    if (tid < NPP) {
        int node = p * NPP + tid;
        if (node < NN) {
            int d = hist[tid];
            if (d > 127) d = 127;             // defensive: keep pack well-formed
            unsigned off = (unsigned)(p * PSTRIDE + boff[tid]);
            pack[node] = (int)((off << 7) | (unsigned)d);
        }
    }
}

// ---------------------------------------------------------------------------
// Kernel 4: gather-sum — barrier-free, LDS-free. One wave per node.
//   g = lane>>3 : edge group; sub = lane&7 : feature quad (8x16B = 128B row)
// ids read directly from sbuf (8-lane duplicate addresses coalesce); 4
// predicated independent id loads -> 4 independent ea loads covers deg<=32
// (P(deg>32 | Poisson 16) ~ 1e-4; rare tail loop beyond). Waves are fully
// independent -> loads stay posted ~all the time (vs 50% with ids-stage
// barrier), occupancy cap 32 waves/CU.
// ---------------------------------------------------------------------------
__global__ __launch_bounds__(256) void gather_kernel(
    const int* __restrict__ pack, const int* __restrict__ sbuf,
    const float* __restrict__ ea, float* __restrict__ agg) {
    int lane = threadIdx.x & 63;
    int node = (blockIdx.x * 256 + threadIdx.x) >> 6;  // grid exact NN/4 blocks
    int pk = pack[node];
    int off = (int)(((unsigned)pk) >> 7);
    int deg = pk & 127;
    int g = lane >> 3, sub = lane & 7;

    int e0 = -1, e1 = -1, e2 = -1, e3 = -1;   // independent id loads
    if (g      < deg) e0 = sbuf[off + g]      & 0x1FFFFF;
    if (g + 8  < deg) e1 = sbuf[off + g + 8]  & 0x1FFFFF;
    if (g + 16 < deg) e2 = sbuf[off + g + 16] & 0x1FFFFF;
    if (g + 24 < deg) e3 = sbuf[off + g + 24] & 0x1FFFFF;

    floatx4 z = {0.f, 0.f, 0.f, 0.f};
    floatx4 acc0 = z, acc1 = z, acc2 = z, acc3 = z;
    if (e0 >= 0) acc0 = *(const floatx4*)(ea + (size_t)e0 * FE + sub * 4);
    if (e1 >= 0) acc1 = *(const floatx4*)(ea + (size_t)e1 * FE + sub * 4);
    if (e2 >= 0) acc2 = *(const floatx4*)(ea + (size_t)e2 * FE + sub * 4);
    if (e3 >= 0) acc3 = *(const floatx4*)(ea + (size_t)e3 * FE + sub * 4);
    for (int j = g + 32; j < deg; j += 8) {   // ~1e-4 of nodes enter
        int e = sbuf[off + j] & 0x1FFFFF;
        acc0 += *(const floatx4*)(ea + (size_t)e * FE + sub * 4);
    }
    acc0 += acc1; acc2 += acc3; acc0 += acc2;

#pragma unroll
    for (int m = 8; m <= 32; m <<= 1) {
#pragma unroll
        for (int c = 0; c < 4; ++c)
            acc0[c] += __shfl_xor(acc0[c], m, 64);
    }
    if (g == 0)
        *(floatx4*)(agg + (size_t)node * FE + sub * 4) = acc0;
}

// ---------------------------------------------------------------------------
// Fallback kernels (atomic path) if ws_size < WS_NEED.
// ---------------------------------------------------------------------------
__global__ __launch_bounds__(256) void zero_probe_kernel(
    float* __restrict__ agg, int* __restrict__ flag, const int* __restrict__ ei) {
    int gid = blockIdx.x * 256 + threadIdx.x;
    floatx4 z = {0.f, 0.f, 0.f, 0.f};
    *(floatx4*)(agg + (size_t)gid * 4) = z;
    if (gid == 0) {
        int orv = 0;
        for (int j = 1; j < 256; j += 2) orv |= ei[j];
        *flag = (orv == 0) ? 1 : 0;
    }
}

__global__ __launch_bounds__(256) void scatter_kernel(
    const int* __restrict__ rows, const float* __restrict__ ea,
    float* __restrict__ agg, const int* __restrict__ flag) {
    int gid = blockIdx.x * 256 + threadIdx.x;
    int e  = gid >> 3;
    int fg = (gid & 7) << 2;
    int is64 = *flag;
    int row = is64 ? rows[2 * (size_t)e] : rows[e];
    floatx4 v = *(const floatx4*)(ea + (size_t)e * FE + fg);
    float* dst = agg + (size_t)row * FE + fg;
#pragma unroll
    for (int j = 0; j < 4; ++j) unsafeAtomicAdd(dst + j, v[j]);
}

// ---------------------------------------------------------------------------
// Kernel 5: fused  out[n] = relu([x@Wx+bx , agg@We+be])  — LDS-free variant.
// One wave per 16-row M-tile; weights loaded as pre-staged bf16 fragments
// from L2-hot wbuf (16B dwordx4 per frag per lane); NO LDS, NO barriers.
// Frag layouts (m89/m91/m120-verified):
//   A: lane l holds A[m=l&15][k=(l>>4)*8+j], j=0..7
//   B: lane l holds B[k=(l>>4)*8+j][n=l&15]
//   D: lane l reg r holds D[(l>>4)*4+r][l&15]
// ---------------------------------------------------------------------------
__global__ __launch_bounds__(256) void fused_gemm_kernel(
    const float* __restrict__ x, const float* __restrict__ agg,
    const short* __restrict__ wbuf, const float* __restrict__ bx,
    const float* __restrict__ be, float* __restrict__ out, int nwaves) {
    const short* wfx = wbuf;                  // [32][64][8]
    const short* wfe = wbuf + WFE_ELEMS;      // [8][64][8]
    int tid = threadIdx.x;
    int wave = tid >> 6, lane = tid & 63;
    int q = lane >> 4, i = lane & 15;

    shortx8 bwe[8];
    float bxv[8], bev[8];
#pragma unroll
    for (int nt = 0; nt < 8; ++nt) {
        bwe[nt] = *(const shortx8*)(wfe + ((size_t)nt * 64 + lane) * 8);
        bxv[nt] = bx[nt * 16 + i];
        bev[nt] = be[nt * 16 + i];
    }

    int gwave = blockIdx.x * 4 + wave;
    for (int mt = gwave; mt < NTILES; mt += nwaves) {
        int m0 = mt << 4;
        int arow = m0 + i;

        const float* xp = x + (size_t)arow * FX + q * 8;
        shortx8 ax[4];
#pragma unroll
        for (int kt = 0; kt < 4; ++kt) {
            floatx4 a0 = *(const floatx4*)(xp + kt * 32);
            floatx4 a1 = *(const floatx4*)(xp + kt * 32 + 4);
#pragma unroll
            for (int j = 0; j < 4; ++j) {
                ax[kt][j]     = (short)f2b(a0[j]);
                ax[kt][4 + j] = (short)f2b(a1[j]);
            }
        }

        const float* ap = agg + (size_t)arow * FE + q * 8;
        floatx4 g0 = *(const floatx4*)ap;
        floatx4 g1 = *(const floatx4*)(ap + 4);
        shortx8 aagg;
#pragma unroll
        for (int j = 0; j < 4; ++j) {
            aagg[j]     = (short)f2b(g0[j]);
            aagg[4 + j] = (short)f2b(g1[j]);
        }

#pragma unroll
        for (int nt = 0; nt < 8; ++nt) {
            floatx4 acc = {0.f, 0.f, 0.f, 0.f};
#pragma unroll
            for (int kt = 0; kt < 4; ++kt) {
                shortx8 b = *(const shortx8*)(wfx + (((size_t)kt * 8 + nt) * 64 + lane) * 8);
                acc = __builtin_amdgcn_mfma_f32_16x16x32_bf16(ax[kt], b, acc, 0, 0, 0);
            }
            floatx4 acche = {0.f, 0.f, 0.f, 0.f};
            acche = __builtin_amdgcn_mfma_f32_16x16x32_bf16(aagg, bwe[nt], acche, 0, 0, 0);
#pragma unroll
            for (int r = 0; r < 4; ++r) {
                int orow = m0 + q * 4 + r;
                float* op = out + (size_t)orow * OUTC + nt * 16 + i;
                float h = acc[r] + bxv[nt];
                op[0]  = h > 0.f ? h : 0.f;
                float g = acche[r] + bev[nt];
                op[OX] = g > 0.f ? g : 0.f;
            }
        }
    }
}

// Fallback GEMM (previous LDS-staging version) for the ws_size-too-small path.
__global__ __launch_bounds__(256) void fused_gemm_lds_kernel(
    const float* __restrict__ x, const float* __restrict__ agg,
    const float* __restrict__ Wx, const float* __restrict__ bx,
    const float* __restrict__ We, const float* __restrict__ be,
    float* __restrict__ out, int nwaves) {
    __shared__ short fragWx[32][64][8];
    __shared__ short fragWe[8][64][8];
    int tid = threadIdx.x;
    for (int c = tid; c < (FX * OX) / 4; c += 256) {
        int base = c * 4;
        int k = base >> 7;
        int n = base & 127;
        floatx4 v = *(const floatx4*)(Wx + base);
        int kt = k >> 5, jj = k & 7, halfk = (k >> 3) & 3;
#pragma unroll
        for (int u = 0; u < 4; ++u) {
            int nn = n + u;
            fragWx[kt * 8 + (nn >> 4)][halfk * 16 + (nn & 15)][jj] = (short)f2b(v[u]);
        }
    }
    for (int c = tid; c < (FE * OE) / 4; c += 256) {
        int base = c * 4;
        int k = base >> 7;
        int n = base & 127;
        floatx4 v = *(const floatx4*)(We + base);
        int jj = k & 7, halfk = (k >> 3) & 3;
#pragma unroll
        for (int u = 0; u < 4; ++u) {
            int nn = n + u;
            fragWe[nn >> 4][halfk * 16 + (nn & 15)][jj] = (short)f2b(v[u]);
        }
    }
    __syncthreads();
    int wave = tid >> 6, lane = tid & 63;
    int q = lane >> 4, i = lane & 15;
    shortx8 bwe[8];
    float bxv[8], bev[8];
#pragma unroll
    for (int nt = 0; nt < 8; ++nt) {
        bwe[nt] = *(const shortx8*)&fragWe[nt][lane][0];
        bxv[nt] = bx[nt * 16 + i];
        bev[nt] = be[nt * 16 + i];
    }
    int gwave = blockIdx.x * 4 + wave;
    for (int mt = gwave; mt < NTILES; mt += nwaves) {
        int m0 = mt << 4;
        int arow = m0 + i;
        const float* xp = x + (size_t)arow * FX + q * 8;
        shortx8 ax[4];
#pragma unroll
        for (int kt = 0; kt < 4; ++kt) {
            floatx4 a0 = *(const floatx4*)(xp + kt * 32);
            floatx4 a1 = *(const floatx4*)(xp + kt * 32 + 4);
#pragma unroll
            for (int j = 0; j < 4; ++j) {
                ax[kt][j]     = (short)f2b(a0[j]);
                ax[kt][4 + j] = (short)f2b(a1[j]);
            }
        }
        const float* ap = agg + (size_t)arow * FE + q * 8;
        floatx4 g0 = *(const floatx4*)ap;
        floatx4 g1 = *(const floatx4*)(ap + 4);
        shortx8 aagg;
#pragma unroll
        for (int j = 0; j < 4; ++j) {
            aagg[j]     = (short)f2b(g0[j]);
            aagg[4 + j] = (short)f2b(g1[j]);
        }
#pragma unroll
        for (int nt = 0; nt < 8; ++nt) {
            floatx4 acc = {0.f, 0.f, 0.f, 0.f};
#pragma unroll
            for (int kt = 0; kt < 4; ++kt) {
                shortx8 b = *(const shortx8*)&fragWx[kt * 8 + nt][lane][0];
                acc = __builtin_amdgcn_mfma_f32_16x16x32_bf16(ax[kt], b, acc, 0, 0, 0);
            }
            floatx4 acche = {0.f, 0.f, 0.f, 0.f};
            acche = __builtin_amdgcn_mfma_f32_16x16x32_bf16(aagg, bwe[nt], acche, 0, 0, 0);
#pragma unroll
            for (int r = 0; r < 4; ++r) {
                int orow = m0 + q * 4 + r;
                float* op = out + (size_t)orow * OUTC + nt * 16 + i;
                float h = acc[r] + bxv[nt];
                op[0]  = h > 0.f ? h : 0.f;
                float g = acche[r] + bev[nt];
                op[OX] = g > 0.f ? g : 0.f;
            }
        }
    }
}

extern "C" void kernel_launch(void* const* d_in, const int* in_sizes, int n_in,
                              void* d_out, int out_size, void* d_ws, size_t ws_size,
                              hipStream_t stream) {
    const float* x  = (const float*)d_in[0];   // [N, FX] f32
    const int*   ei = (const int*)d_in[1];     // [2, E] int (width probed)
    const float* ea = (const float*)d_in[2];   // [E, FE] f32
    const float* Wx = (const float*)d_in[3];   // [FX, OX] f32
    const float* bx = (const float*)d_in[4];   // [OX] f32
    const float* We = (const float*)d_in[5];   // [FE, OE] f32
    const float* be = (const float*)d_in[6];   // [OE] f32
    float* out = (float*)d_out;                // [N, 256] f32

    float* agg  = (float*)d_ws;
    int*   flagC= (int*)((char*)d_ws + FLAG_OFF);
    int*   pcur = (int*)((char*)d_ws + PCUR_OFF);
    int*   pbuf = (int*)((char*)d_ws + PBUF_OFF);
    int*   sbuf = (int*)((char*)d_ws + SBUF_OFF);
    int*   pack = (int*)((char*)d_ws + PACK_OFF);
    short* wbuf = (short*)((char*)d_ws + WBUF_OFF);

    const int blocks = 1563;  // 1563 x 4 waves = 6252 >= 6250 tiles

    if (ws_size >= WS_NEED) {
        // ---- partition + counting-sort CSR path ----
        prep_kernel<<<20, 256, 0, stream>>>(Wx, We, wbuf);
        init_kernel<<<(NPART * PCPAD / 4 + 255) / 256, 256, 0, stream>>>(pcur, flagC, ei);
        part_kernel<<<(EE + 8191) / 8192, 1024, 0, stream>>>(ei, flagC, pcur, pbuf);
        sort_kernel<<<NPART, 256, 0, stream>>>(pcur, pbuf, sbuf, pack);
        gather_kernel<<<NN / 4, 256, 0, stream>>>(pack, sbuf, ea, agg);
        fused_gemm_kernel<<<blocks, 256, 0, stream>>>(x, agg, wbuf, bx, be, out,
                                                      blocks * 4);
    } else {
        // ---- fallback: atomic scatter + LDS-staging gemm ----
        int* flagA = (int*)((char*)d_ws + AGG_BYTES);
        zero_probe_kernel<<<(NN * FE) / 4 / 256, 256, 0, stream>>>(agg, flagA, ei);
        scatter_kernel<<<(EE * 8) / 256, 256, 0, stream>>>(ei, ea, agg, flagA);
        fused_gemm_lds_kernel<<<blocks, 256, 0, stream>>>(x, agg, Wx, bx, We, be,
                                                          out, blocks * 4);
    }
}